// Round 1
// baseline (319.261 us; speedup 1.0000x reference)
//
#include <hip/hip_runtime.h>
#include <hip/hip_bf16.h>
#include <stdint.h>

#define NTOK 8192
#define DIM  512
#define QKVW 1536

typedef __attribute__((ext_vector_type(8))) short bf16x8;
typedef __attribute__((ext_vector_type(4))) float f32x4;

static __device__ __forceinline__ unsigned short f2b(float f) {
    union { float f; unsigned int u; } v; v.f = f;
    unsigned int r = v.u + 0x7fffu + ((v.u >> 16) & 1u);
    return (unsigned short)(r >> 16);
}

static __device__ __forceinline__ void gld_lds16(const void* g, void* l) {
    __builtin_amdgcn_global_load_lds(
        (__attribute__((address_space(1))) void*)(uintptr_t)g,
        (__attribute__((address_space(3))) void*)(uintptr_t)l,
        16, 0, 0);
}

// ---------------- converts ----------------

__global__ void f2b_kernel(const float* __restrict__ src, unsigned short* __restrict__ dst, int n4) {
    int i = blockIdx.x * blockDim.x + threadIdx.x;
    if (i < n4) {
        float4 f = ((const float4*)src)[i];
        ushort4 o;
        o.x = f2b(f.x); o.y = f2b(f.y); o.z = f2b(f.z); o.w = f2b(f.w);
        ((ushort4*)dst)[i] = o;
    }
}

__global__ void bias_concat(const float* __restrict__ bq, const float* __restrict__ bk,
                            const float* __restrict__ bv, float* __restrict__ bc) {
    int i = blockIdx.x * blockDim.x + threadIdx.x;
    if (i < 512)       bc[i] = bq[i];
    else if (i < 1024) bc[i] = bk[i - 512];
    else if (i < 1536) bc[i] = bv[i - 1024];
}

// ---------------- V transpose ----------------
// V[j][d] = qkv[j*1536 + 1024 + d]  ->  Vt[d][j]
__global__ void transpose_v(const unsigned short* __restrict__ qkv, unsigned short* __restrict__ vt) {
    __shared__ unsigned short t[64][65];
    int j0 = blockIdx.x * 64;   // 128 blocks over token dim
    int d0 = blockIdx.y * 64;   // 8 blocks over feature dim
    int tid = threadIdx.x;
    int c  = tid & 63;
    int r4 = tid >> 6;
    #pragma unroll
    for (int r = r4; r < 64; r += 4)
        t[r][c] = qkv[(size_t)(j0 + r) * QKVW + 1024 + d0 + c];
    __syncthreads();
    #pragma unroll
    for (int r = r4; r < 64; r += 4)
        vt[(size_t)(d0 + r) * NTOK + j0 + c] = t[c][r];
}

// ---------------- GEMM C = A * B^T  (A [M,K], B [N,K], both bf16 row-major) ----------------
// EPI 0: bf16 store + bias[col]          (QKV projection)
// EPI 1: bf16 store + atomic row sum-sq  (S = Q K^T)
// EPI 2: fp32 store * rsqrt(rowss[row])  (O = S V)
template <int EPI>
__global__ __launch_bounds__(256, 2) void gemm_bt(
    const unsigned short* __restrict__ A, int lda,
    const unsigned short* __restrict__ B, int ldb,
    int K,
    void* __restrict__ Cout, int ldc,
    const float* __restrict__ bias,
    float* __restrict__ rowss) {

    __shared__ __align__(16) unsigned short lsA[128 * 32];
    __shared__ __align__(16) unsigned short lsB[128 * 32];

    const int tid  = threadIdx.x;
    const int lane = tid & 63;
    const int wid  = tid >> 6;
    const int bm = blockIdx.y, bn = blockIdx.x;
    const int wr = wid >> 1, wc = wid & 1;

    f32x4 acc[4][4] = {};

    const unsigned short* Abase = A + (size_t)(bm * 128) * lda;
    const unsigned short* Bbase = B + (size_t)(bn * 128) * ldb;

    const int lk = (lane >> 4) * 8;  // k-offset within 32-wide K-step
    const int lr = lane & 15;

    for (int kt = 0; kt < K; kt += 32) {
        // stage A,B tiles (128x32 bf16 each) via direct global->LDS, 16B/lane
        #pragma unroll
        for (int q = 0; q < 2; ++q) {
            int cb  = (wid * 2 + q) * 64;       // wave-uniform chunk base
            int c   = cb + lane;                // this lane's 16B chunk
            int row = c >> 2;
            int col = (c & 3) * 8;
            gld_lds16(Abase + (size_t)row * lda + kt + col, &lsA[cb * 8]);
            gld_lds16(Bbase + (size_t)row * ldb + kt + col, &lsB[cb * 8]);
        }
        __syncthreads();

        bf16x8 af[4], bf[4];
        #pragma unroll
        for (int m = 0; m < 4; ++m)
            af[m] = *(const bf16x8*)&lsA[(wr * 64 + m * 16 + lr) * 32 + lk];
        #pragma unroll
        for (int n = 0; n < 4; ++n)
            bf[n] = *(const bf16x8*)&lsB[(wc * 64 + n * 16 + lr) * 32 + lk];

        #pragma unroll
        for (int m = 0; m < 4; ++m)
            #pragma unroll
            for (int n = 0; n < 4; ++n)
                acc[m][n] = __builtin_amdgcn_mfma_f32_16x16x32_bf16(af[m], bf[n], acc[m][n], 0, 0, 0);
        __syncthreads();
    }

    const int rbase = bm * 128 + wr * 64;
    const int cbase = bn * 128 + wc * 64;
    const int rlane = (lane >> 4) * 4;  // row sub-offset, + j
    const int clane = lane & 15;        // col sub-offset

    if (EPI == 0) {
        unsigned short* C = (unsigned short*)Cout;
        #pragma unroll
        for (int m = 0; m < 4; ++m)
            #pragma unroll
            for (int n = 0; n < 4; ++n)
                #pragma unroll
                for (int j = 0; j < 4; ++j) {
                    int r = rbase + m * 16 + rlane + j;
                    int c = cbase + n * 16 + clane;
                    C[(size_t)r * ldc + c] = f2b(acc[m][n][j] + bias[c]);
                }
    } else if (EPI == 1) {
        unsigned short* C = (unsigned short*)Cout;
        #pragma unroll
        for (int m = 0; m < 4; ++m)
            #pragma unroll
            for (int n = 0; n < 4; ++n)
                #pragma unroll
                for (int j = 0; j < 4; ++j) {
                    int r = rbase + m * 16 + rlane + j;
                    int c = cbase + n * 16 + clane;
                    C[(size_t)r * ldc + c] = f2b(acc[m][n][j]);
                }
        // per-row partial sum of squares over this wave's 64 cols
        #pragma unroll
        for (int m = 0; m < 4; ++m)
            #pragma unroll
            for (int j = 0; j < 4; ++j) {
                float p = 0.f;
                #pragma unroll
                for (int n = 0; n < 4; ++n) {
                    float v = acc[m][n][j];
                    p += v * v;
                }
                p += __shfl_xor(p, 1);
                p += __shfl_xor(p, 2);
                p += __shfl_xor(p, 4);
                p += __shfl_xor(p, 8);
                if ((lane & 15) == 0)
                    atomicAdd(&rowss[rbase + m * 16 + rlane + j], p);
            }
    } else {
        float* C = (float*)Cout;
        #pragma unroll
        for (int m = 0; m < 4; ++m)
            #pragma unroll
            for (int j = 0; j < 4; ++j) {
                int r = rbase + m * 16 + rlane + j;
                float sc = 1.0f / fmaxf(sqrtf(rowss[r]), 1e-12f);
                #pragma unroll
                for (int n = 0; n < 4; ++n)
                    C[(size_t)r * ldc + cbase + n * 16 + clane] = acc[m][n][j] * sc;
            }
    }
}

extern "C" void kernel_launch(void* const* d_in, const int* in_sizes, int n_in,
                              void* d_out, int out_size, void* d_ws, size_t ws_size,
                              hipStream_t stream) {
    const float* x  = (const float*)d_in[0];
    const float* Wq = (const float*)d_in[1];
    const float* bq = (const float*)d_in[2];
    const float* Wk = (const float*)d_in[3];
    const float* bk = (const float*)d_in[4];
    const float* Wv = (const float*)d_in[5];
    const float* bv = (const float*)d_in[6];
    float* out = (float*)d_out;

    char* ws = (char*)d_ws;
    size_t off = 0;
    auto alloc = [&](size_t bytes) -> void* {
        void* p = ws + off;
        off = (off + bytes + 255) & ~(size_t)255;
        return p;
    };

    unsigned short* xb  = (unsigned short*)alloc((size_t)NTOK * DIM * 2);
    unsigned short* Wb  = (unsigned short*)alloc((size_t)QKVW * DIM * 2);
    float*          bc  = (float*)alloc(QKVW * 4);
    unsigned short* QKV = (unsigned short*)alloc((size_t)NTOK * QKVW * 2);
    unsigned short* Vt  = (unsigned short*)alloc((size_t)DIM * NTOK * 2);
    float*          rss = (float*)alloc(NTOK * 4);
    unsigned short* S   = (unsigned short*)alloc((size_t)NTOK * NTOK * 2);

    // converts
    f2b_kernel<<<(NTOK * DIM / 4 + 255) / 256, 256, 0, stream>>>(x, xb, NTOK * DIM / 4);
    f2b_kernel<<<(DIM * DIM / 4 + 255) / 256, 256, 0, stream>>>(Wq, Wb, DIM * DIM / 4);
    f2b_kernel<<<(DIM * DIM / 4 + 255) / 256, 256, 0, stream>>>(Wk, Wb + DIM * DIM, DIM * DIM / 4);
    f2b_kernel<<<(DIM * DIM / 4 + 255) / 256, 256, 0, stream>>>(Wv, Wb + 2 * DIM * DIM, DIM * DIM / 4);
    bias_concat<<<6, 256, 0, stream>>>(bq, bk, bv, bc);
    hipMemsetAsync(rss, 0, NTOK * 4, stream);

    // QKV = x @ Wb^T + bias   [8192 x 1536], K=512
    {
        dim3 g(QKVW / 128, NTOK / 128);
        gemm_bt<0><<<g, 256, 0, stream>>>(xb, DIM, Wb, DIM, DIM, QKV, QKVW, bc, nullptr);
    }

    // Vt[d][j] from QKV's V block
    transpose_v<<<dim3(NTOK / 64, DIM / 64), 256, 0, stream>>>(QKV, Vt);

    // S = Q @ K^T  [8192 x 8192], K=512 ; also rowss += per-row sumsq
    {
        dim3 g(NTOK / 128, NTOK / 128);
        gemm_bt<1><<<g, 256, 0, stream>>>(QKV, QKVW, QKV + DIM, QKVW, DIM, S, NTOK, nullptr, rss);
    }

    // O = (S @ Vt^T) * rsqrt(rowss)  [8192 x 512], K=8192
    {
        dim3 g(DIM / 128, NTOK / 128);
        gemm_bt<2><<<g, 256, 0, stream>>>(S, NTOK, Vt, NTOK, NTOK, out, DIM, nullptr, rss);
    }
}